// Round 8
// baseline (142.296 us; speedup 1.0000x reference)
//
#include <hip/hip_runtime.h>
#include <math.h>

#define B_SZ 256
#define N_SZ 1024
#define D_MODEL 128
#define NUM_CLASSES 32

// exp(-ETA*d^2) = 2^(d^2 * -ETA*log2(e));  -4 * 1.4426950408889634
#define K_EXP (-5.770780163555854f)
// cos(pi*rc/RC) with v_cos (revolutions): arg = rc/(2*RC) = rc/12
#define K_COS (1.0f / 12.0f)

__device__ __forceinline__ void compute_prod(const float4 xv, float& r, int& c, float p[4]) {
    const float y00 = 0.28209479177387814f;  // 0.5/sqrt(pi)
    const float c1  = 0.48860251190291992f;  // sqrt(3/(4pi))
    float r2 = xv.x * xv.x + xv.y * xv.y + xv.z * xv.z;
    r = sqrtf(r2);
    c = (int)xv.w;
    float inv_r = (r > 0.0f) ? __builtin_amdgcn_rcpf(r) : 0.0f;
    float ux = xv.x * inv_r, uy = xv.y * inv_r, uz = xv.z * inv_r;
    float rc = fminf(r, 6.0f);
    float env = 0.5f * __builtin_amdgcn_cosf(rc * K_COS) + 0.5f;
    float d0 = 0.0f - r, d1 = 1.5f - r, d2 = 3.0f - r, d3 = 4.5f - r;
    float rad0 = __builtin_amdgcn_exp2f(d0 * d0 * K_EXP);
    float rad1 = __builtin_amdgcn_exp2f(d1 * d1 * K_EXP);
    float rad2 = __builtin_amdgcn_exp2f(d2 * d2 * K_EXP);
    float rad3 = __builtin_amdgcn_exp2f(d3 * d3 * K_EXP);
    p[0] = y00 * rad0 * env;
    p[1] = c1 * uy * rad1 * env;
    p[2] = c1 * uz * rad2 * env;
    p[3] = c1 * ux * rad3 * env;
}

// Prep: one block per batch, one point per thread. Does the per-batch L2-norm
// reduction AND the per-point layernorm closed form, emitting a 24B record:
//   recA[pt] = float4(amb0, amb1, amb2, amb3)   (normalized "hit" values)
//   recB[pt] = float2(bneg, bitcast(class))     (background value + class)
__global__ __launch_bounds__(1024) void ape_prep_kernel(const float* __restrict__ x,
                                                        float4* __restrict__ recA,
                                                        float2* __restrict__ recB) {
    __shared__ float nsq[D_MODEL];
    __shared__ float invn[D_MODEL];
    const int b = blockIdx.x;
    const int t = threadIdx.x;
    if (t < D_MODEL) nsq[t] = 0.0f;
    __syncthreads();

    float4 xv = ((const float4*)x)[(size_t)b * N_SZ + t];
    float r; int c; float p[4];
    compute_prod(xv, r, c, p);
    if (r <= 0.0f) { p[0] = p[1] = p[2] = p[3] = 0.0f; }
    if (r > 0.0f) {
        atomicAdd(&nsq[0 * NUM_CLASSES + c], p[0] * p[0]);
        atomicAdd(&nsq[1 * NUM_CLASSES + c], p[1] * p[1]);
        atomicAdd(&nsq[2 * NUM_CLASSES + c], p[2] * p[2]);
        atomicAdd(&nsq[3 * NUM_CLASSES + c], p[3] * p[3]);
    }
    __syncthreads();
    if (t < D_MODEL) {
        invn[t] = __builtin_amdgcn_rcpf(fmaxf(sqrtf(nsq[t]), 1e-12f));
    }
    __syncthreads();

    float pn0 = p[0] * invn[0 * NUM_CLASSES + c];
    float pn1 = p[1] * invn[1 * NUM_CLASSES + c];
    float pn2 = p[2] * invn[2 * NUM_CLASSES + c];
    float pn3 = p[3] * invn[3 * NUM_CLASSES + c];
    float sum = pn0 + pn1 + pn2 + pn3;
    float mean = sum * (1.0f / 128.0f);
    float sumsq = pn0 * pn0 + pn1 * pn1 + pn2 * pn2 + pn3 * pn3;
    float var = fmaxf((sumsq - 128.0f * mean * mean) * (1.0f / 127.0f), 0.0f);
    float inv_std = __builtin_amdgcn_rcpf(sqrtf(var) + 1e-6f);
    float bneg = -mean * inv_std;
    // r<=0: p=0 -> pn=0 -> mean=0, var=0, bneg=0, amb=0 -> all-zero row (matches ref)
    const size_t pt = (size_t)b * N_SZ + t;
    recA[pt] = make_float4(pn0 * inv_std + bneg, pn1 * inv_std + bneg,
                           pn2 * inv_std + bneg, pn3 * inv_std + bneg);
    recB[pt] = make_float2(bneg, __int_as_float(c));
}

// Writer: pure store stream. No LDS, no barriers, tiny VGPR -> high occupancy,
// stores issue from cycle ~0. 4 lanes per point; store j covers features
// [j*16 + sub*4, +4) at byte pt*512 + j*64 + sub*16 -> each wave store
// instruction covers 16 full 64B cachelines.
__global__ __launch_bounds__(256) void ape_write_kernel(const float4* __restrict__ recA,
                                                        const float2* __restrict__ recB,
                                                        float* __restrict__ out) {
    const int gid = blockIdx.x * 256 + threadIdx.x;
    const int pt = gid >> 2;
    const int sub = gid & 3;

    const float4 amb4 = recA[pt];   // 4 lanes same addr -> broadcast
    const float2 bb = recB[pt];
    const float bneg = bb.x;
    const int c = __float_as_int(bb.y);
    const float amb[4] = {amb4.x, amb4.y, amb4.z, amb4.w};

    float4* ob = (float4*)out + (size_t)pt * 32 + sub;
    const int hb = sub * 4;
#pragma unroll
    for (int j = 0; j < 8; ++j) {
        const float a = amb[j >> 1];
        const int cb = (j & 1) * 16 + hb;
        float4 o;
        o.x = (cb + 0 == c) ? a : bneg;
        o.y = (cb + 1 == c) ? a : bneg;
        o.z = (cb + 2 == c) ? a : bneg;
        o.w = (cb + 3 == c) ? a : bneg;
        ob[j * 4] = o;
    }
}

extern "C" void kernel_launch(void* const* d_in, const int* in_sizes, int n_in,
                              void* d_out, int out_size, void* d_ws, size_t ws_size,
                              hipStream_t stream) {
    const float* x = (const float*)d_in[0];
    float* out = (float*)d_out;
    float4* recA = (float4*)d_ws;                              // 1M * 16B = 16 MB
    float2* recB = (float2*)((char*)d_ws + (size_t)B_SZ * N_SZ * sizeof(float4));  // 8 MB

    ape_prep_kernel<<<B_SZ, 1024, 0, stream>>>(x, recA, recB);

    const int total_threads = B_SZ * N_SZ * 4;  // 4 lanes per point
    ape_write_kernel<<<total_threads / 256, 256, 0, stream>>>(recA, recB, out);
}